// Round 6
// baseline (601.627 us; speedup 1.0000x reference)
//
#include <hip/hip_runtime.h>
#include <math.h>
#include <stdint.h>

// NeuralMJP forward, MI355X/gfx950.
//  * sample == one-hot(argmax(logits)) in fwd -> decoder = 32x32 table.
//  * argmax(softmax(z)) == argmax(z) -> y never materialized.
//  * fp32 only (no fp32 MFMA; bf16 flips Gumbel argmaxes -> catastrophic).
//  * Weight-delivery ladder:
//      R1 all-SMEM scalar fmac: per-j lgkmcnt(0) drain -> 38% VALU, 670us.
//      R2 LDS 16x uniform b128/j: DS-pipe-bound, 818us.
//      R4 VMEM: L1 returns 1KiB/wave-load, 1530us.
//      R5 LDS quad-split + DPP-fmac: 558us (DPP fmac ~6cyc issue).
//      R6 scalar w1 + DPP w2: 509us; ~50k of 111k cyc/wave = DPP tax.
//      R7 both-phase SGPR + v_pk_fma_f32: 820us (pk_fma ~6cyc, not 2x).
//      R8 quad-coop phase-2 (activation bcast via 3 DPP movs): VALU/wave
//         111k->90k, but 54KB LDS -> 2 blocks/CU -> 52% busy, 578us.
//      R9 16KB overlay LDS but launch_bounds(256,4) -> VGPR 64 -> spills.
//      R10 launch_bounds(256,3): 458us, VALU 66%. Remaining 34% idle =
//          mixed SMEM+DS on ONE lgkmcnt counter -> per-j lgkmcnt(0) drains.
//      R11 pure-DS loop (w1 in LDS, quad partial dots + v_add_f32_dpp
//          XOR-reduce) FAILED absmax 1.3. Audit: exchange/reduce/transpose
//          bitwise-sound; prime suspect = global_load_lds with per-lane
//          LDS ptr (wave-uniform-base+lane*16 semantics, unvalidated here).
//      R12 (this): R11 structure, proven mechanisms only:
//          - staging via float4 reg-relay (R10-proven), relay loads issued
//            at epilogue top so HBM latency hides under transpose+softmax;
//          - h-exchange write-once/read-once across the full 32KB slab
//            (no address reuse, no divergent publish);
//          - keep DPP add-reduce (only remaining unproven piece ->
//            differential debugging if absmax != 0).

constexpr int kB = 524288;  // batch
constexpr int kD = 32;      // input dim
constexpr int kH = 128;     // hidden
constexpr int kS = 32;      // states

// d_ws layout (bytes):
//   pw1   @ 0     : 3*128*32 f32 = 49152   row j of pass p = w1_p[:,j]
//   pb1   @ 49152 : 3*128   f32 = 1536
//   table @ 50688 : 32*32   f32 = 4096

// -------- prep: pack w1 (transposed) + b1 + decoder table -----------------
__global__ __launch_bounds__(1024) void prep_kernel(
    const float* __restrict__ q_w1,  const float* __restrict__ q_b1,
    const float* __restrict__ gi_w1, const float* __restrict__ gi_b1,
    const float* __restrict__ go_w1, const float* __restrict__ go_b1,
    const float* __restrict__ dec_w1, const float* __restrict__ dec_b1,
    const float* __restrict__ dec_w2, const float* __restrict__ dec_b2,
    float* __restrict__ pw1, float* __restrict__ pb1, float* __restrict__ table)
{
    const int t = threadIdx.x;
    // decoder table: row k = relu(dec_w1[k,:] + dec_b1) @ dec_w2 + dec_b2
    {
        const int k = t >> 5, d = t & 31;
        float acc = 0.0f;
        #pragma unroll 4
        for (int j = 0; j < kH; ++j) {
            float a = dec_w1[k * kH + j] + dec_b1[j];
            a = fmaxf(a, 0.0f);
            acc = fmaf(a, dec_w2[j * kS + d], acc);
        }
        table[k * kS + d] = acc + dec_b2[d];
    }
    // w1 transposed pack: 3*128 rows of 32 floats + compact b1 slab
    if (t < 3 * kH) {
        const int p = t >> 7;
        const int j = t & (kH - 1);
        const float* w1 = (p == 0) ? q_w1 : (p == 1) ? gi_w1 : go_w1;
        const float* b1 = (p == 0) ? q_b1 : (p == 1) ? gi_b1 : go_b1;
        float* row = pw1 + (size_t)(p * kH + j) * 32;
        for (int i = 0; i < kD; ++i) row[i] = w1[i * kH + j];
        pb1[t] = b1[j];
    }
}

// -------- main ------------------------------------------------------------
// 2-round quad XOR-reduce via v_add_f32_dpp (DPP on src0). After round 2
// every quad lane holds ((c0+c1)+(c2+c3)) per element, bit-exact vs np (IEEE
// add commutativity only). s_nop 1 covers VALU->DPP wait states.
#define QRED(o0, o1, o2, o3, s0, s1, s2, s3, PERM) \
    asm("s_nop 1\n\t" \
        "v_add_f32_dpp %0, %4, %4 " PERM " row_mask:0xf bank_mask:0xf\n\t" \
        "v_add_f32_dpp %1, %5, %5 " PERM " row_mask:0xf bank_mask:0xf\n\t" \
        "v_add_f32_dpp %2, %6, %6 " PERM " row_mask:0xf bank_mask:0xf\n\t" \
        "v_add_f32_dpp %3, %7, %7 " PERM " row_mask:0xf bank_mask:0xf" \
        : "=&v"(o0), "=&v"(o1), "=&v"(o2), "=&v"(o3) \
        : "v"(s0), "v"(s1), "v"(s2), "v"(s3))

// Per j: lane reads w1 slice [8l..8l+7] (2x b128) + w2 slice {4l..,16+4l..}
// (2x b128); 4 partial dots over quad-exchanged hq; DPP XOR-reduce -> all 4
// activations in-lane; 32 plain fmacs rank-1. L bank r = element r, s-slice
// {4l..4l+3, 16+4l..16+4l+3}; j-ascending per accumulator (np order).
__device__ __forceinline__ void mlp_pass(const float* __restrict__ hq,
                                         const float* __restrict__ w1q,  // slab + 8l
                                         const float* __restrict__ w2q,  // slab+4096 + 4l
                                         float b1lo, float b1hi,
                                         float* __restrict__ L)
{
    #pragma unroll
    for (int s = 0; s < kS; ++s) L[s] = 0.0f;
    #pragma unroll 2
    for (int j = 0; j < kH; ++j) {
        const float4 U0 = *reinterpret_cast<const float4*>(w1q + j * 32);
        const float4 U1 = *reinterpret_cast<const float4*>(w1q + j * 32 + 4);
        const float4 W0 = *reinterpret_cast<const float4*>(w2q + j * 32);
        const float4 W1 = *reinterpret_cast<const float4*>(w2q + j * 32 + 16);
        const float bsel = (j < 64) ? b1lo : b1hi;
        const float bias = __uint_as_float(
            (unsigned)__builtin_amdgcn_readlane((int)__float_as_uint(bsel), j & 63));
        // 4 partial dots (my 8-dim slice of each quad element, i ascending)
        float p0 = 0.f, p1 = 0.f, p2 = 0.f, p3 = 0.f;
        #define ST(i, u) \
            p0 = fmaf(hq[0 + (i)], (u), p0);  p1 = fmaf(hq[8 + (i)], (u), p1); \
            p2 = fmaf(hq[16 + (i)], (u), p2); p3 = fmaf(hq[24 + (i)], (u), p3);
        ST(0, U0.x) ST(1, U0.y) ST(2, U0.z) ST(3, U0.w)
        ST(4, U1.x) ST(5, U1.y) ST(6, U1.z) ST(7, U1.w)
        #undef ST
        // quad XOR-reduce: d_e = ((c0+c1)+(c2+c3)) for element e, all lanes
        float t0, t1, t2, t3, d0, d1, d2, d3;
        QRED(t0, t1, t2, t3, p0, p1, p2, p3, "quad_perm:[1,0,3,2]");
        QRED(d0, d1, d2, d3, t0, t1, t2, t3, "quad_perm:[2,3,0,1]");
        const float a0 = fmaxf(d0 + bias, 0.0f);
        const float a1 = fmaxf(d1 + bias, 0.0f);
        const float a2 = fmaxf(d2 + bias, 0.0f);
        const float a3 = fmaxf(d3 + bias, 0.0f);
        // rank-1 update: 32 plain fmacs, j-ascending per (element,s) accum
        #define P2(k, w) \
            L[k]      = fmaf(a0, w, L[k]);      L[8 + k]  = fmaf(a1, w, L[8 + k]); \
            L[16 + k] = fmaf(a2, w, L[16 + k]); L[24 + k] = fmaf(a3, w, L[24 + k]);
        P2(0, W0.x) P2(1, W0.y) P2(2, W0.z) P2(3, W0.w)
        P2(4, W1.x) P2(5, W1.y) P2(6, W1.z) P2(7, W1.w)
        #undef P2
    }
}

// b2 added in slice layout (same value pattern for all 4 element banks).
__device__ __forceinline__ void add_b2_slice(float* __restrict__ L,
                                             const float4 B0, const float4 B1)
{
    #pragma unroll
    for (int r = 0; r < 4; ++r) {
        L[r*8+0] += B0.x; L[r*8+1] += B0.y; L[r*8+2] += B0.z; L[r*8+3] += B0.w;
        L[r*8+4] += B1.x; L[r*8+5] += B1.y; L[r*8+6] += B1.z; L[r*8+7] += B1.w;
    }
}

// One 16-value round of the wave-synchronous quad transpose through the
// wave's private quarter of the (dead) w1 region. Intra-wave DS ordering
// (write->read, and cross-round address reuse) proven in R9/R10.
// Round R: L bank r regs [r*8+R*4..+3] = (element r, s = R*16+4l+k).
__device__ __forceinline__ void quad_transpose16(float* __restrict__ qb,
                                                 int l, int xq, int R,
                                                 const float* __restrict__ L,
                                                 float* __restrict__ lg)
{
    #pragma unroll
    for (int r = 0; r < 4; ++r) {
        *reinterpret_cast<float4*>(qb + r * 16 + ((4 * l) ^ xq)) =
            make_float4(L[r*8 + R*4 + 0], L[r*8 + R*4 + 1],
                        L[r*8 + R*4 + 2], L[r*8 + R*4 + 3]);
    }
    #pragma unroll
    for (int c = 0; c < 4; ++c) {
        const float4 v = *reinterpret_cast<const float4*>(qb + l * 16 + ((4 * c) ^ xq));
        lg[R*16 + 4*c + 0] = v.x; lg[R*16 + 4*c + 1] = v.y;
        lg[R*16 + 4*c + 2] = v.z; lg[R*16 + 4*c + 3] = v.w;
    }
}

__device__ __forceinline__ float tree_sum32(const float* __restrict__ v)
{
    float b0 = 0.f, b1 = 0.f, b2 = 0.f, b3 = 0.f;
    #pragma unroll
    for (int i = 0; i < 8; ++i) {
        b0 += v[i]; b1 += v[i + 8]; b2 += v[i + 16]; b3 += v[i + 24];
    }
    return (b0 + b1) + (b2 + b3);   // pairwise-ish, like np.sum
}

__device__ __forceinline__ void softmax32(const float* __restrict__ lg,
                                          float* __restrict__ p)
{
    float m = lg[0];
    #pragma unroll
    for (int s = 1; s < kS; ++s) m = fmaxf(m, lg[s]);
    float e[kS];
    #pragma unroll
    for (int s = 0; s < kS; ++s) e[s] = expf(lg[s] - m);
    const float Z = tree_sum32(e);
    #pragma unroll
    for (int s = 0; s < kS; ++s) p[s] = e[s] / Z;  // precise div, like np
}

__global__ __launch_bounds__(256, 3) void main_kernel(
    const float* __restrict__ h, const float* __restrict__ u,
    const float* __restrict__ qb2, const float* __restrict__ gib2,
    const float* __restrict__ gob2,
    const float* __restrict__ q_w2, const float* __restrict__ gi_w2,
    const float* __restrict__ go_w2,
    const float* __restrict__ pw1, const float* __restrict__ pb1,
    const float* __restrict__ table, float* __restrict__ out)
{
    __shared__ float slab[2 * kH * kS];  // 32KB. [0..4096): w1 rows of the
                                         // current pass (+ transpose scratch
                                         // overlay between passes);
                                         // [4096..8192): w2 rows. The whole
                                         // slab doubles as h-exchange
                                         // scratch before first staging.

    const int tid = threadIdx.x;
    const int lane = tid & 63;
    const int b = blockIdx.x * 256 + tid;
    const int l = tid & 3;              // quad pos == element slot
    const int qg = (tid >> 2) & 15;     // quad within wave
    const int xq = (qg & 3) << 2;       // XOR slot swizzle
    float* const qb = slab + (tid >> 6) * 1024 + qg * 64;   // transpose scratch
    float* const qx = slab + (tid >> 6) * 2048 + qg * 128;  // h-exchange scratch
    const float* __restrict__ w1q = slab + 8 * l;
    const float* __restrict__ w2q = slab + kH * kS + 4 * l;
    float4* const d4 = reinterpret_cast<float4*>(slab);

    // ---- load h; issue pass-0 relay loads early (hide under exchange) ----
    float hv[kD];
    {
        const float4* h4 = reinterpret_cast<const float4*>(h + (size_t)b * kD);
        #pragma unroll
        for (int i = 0; i < 8; ++i) {
            float4 t = h4[i];
            hv[4 * i + 0] = t.x; hv[4 * i + 1] = t.y;
            hv[4 * i + 2] = t.z; hv[4 * i + 3] = t.w;
        }
    }
    float4 ra[4], rb[4];
    {
        const float4* s1 = reinterpret_cast<const float4*>(pw1);
        const float4* s2 = reinterpret_cast<const float4*>(q_w2);
        #pragma unroll
        for (int k = 0; k < 4; ++k) { ra[k] = s1[k * 256 + tid]; rb[k] = s2[k * 256 + tid]; }
    }

    // ---- quad h-exchange over the full slab: write once, read once ------
    // hq[e*8+i] = h of quad element e, dim 8l+i.
    float hq[kD];
    {
        #pragma unroll
        for (int i = 0; i < 8; ++i)
            *reinterpret_cast<float4*>(qx + l * 32 + ((4 * i) ^ xq)) =
                make_float4(hv[4*i], hv[4*i+1], hv[4*i+2], hv[4*i+3]);
        #pragma unroll
        for (int e = 0; e < 4; ++e) {
            #pragma unroll
            for (int k = 0; k < 2; ++k) {
                const float4 v = *reinterpret_cast<const float4*>(
                    qx + e * 32 + ((8 * l + 4 * k) ^ xq));
                hq[e*8 + 4*k + 0] = v.x; hq[e*8 + 4*k + 1] = v.y;
                hq[e*8 + 4*k + 2] = v.z; hq[e*8 + 4*k + 3] = v.w;
            }
        }
    }
    __syncthreads();   // exchange reads done -> slab stageable

    // ---- stage pass-0 slabs (proven float4 relay) ----
    #pragma unroll
    for (int k = 0; k < 4; ++k) {
        d4[k * 256 + tid] = ra[k];
        d4[1024 + k * 256 + tid] = rb[k];
    }
    __syncthreads();   // pass-0 slabs ready

    float L[kS], lg[kS], q[kS], gi[kS];

    // ---- pass 0 (q) ----
    {
        const float4 B0 = *reinterpret_cast<const float4*>(qb2 + 4 * l);
        const float4 B1 = *reinterpret_cast<const float4*>(qb2 + 16 + 4 * l);
        mlp_pass(hq, w1q, w2q, pb1[lane], pb1[64 + lane], L);
        add_b2_slice(L, B0, B1);
    }
    __syncthreads();   // A: pass-0 slabs dead
    {
        const float4* s1 = reinterpret_cast<const float4*>(pw1 + kH * kD);
        const float4* s2 = reinterpret_cast<const float4*>(gi_w2);
        #pragma unroll
        for (int k = 0; k < 4; ++k) { ra[k] = s1[k * 256 + tid]; rb[k] = s2[k * 256 + tid]; }
        quad_transpose16(qb, l, xq, 0, L, lg);
        quad_transpose16(qb, l, xq, 1, L, lg);
        softmax32(lg, q);
        // w2 region untouched since A -> safe to restage before B
        #pragma unroll
        for (int k = 0; k < 4; ++k) d4[1024 + k * 256 + tid] = rb[k];
    }
    __syncthreads();   // B: all scratch reads done -> w1 region writable
    #pragma unroll
    for (int k = 0; k < 4; ++k) d4[k * 256 + tid] = ra[k];
    __syncthreads();   // C: pass-1 slabs ready

    // ---- pass 1 (g_in) ----
    {
        const float4 B0 = *reinterpret_cast<const float4*>(gib2 + 4 * l);
        const float4 B1 = *reinterpret_cast<const float4*>(gib2 + 16 + 4 * l);
        mlp_pass(hq, w1q, w2q, pb1[128 + lane], pb1[192 + lane], L);
        add_b2_slice(L, B0, B1);
    }
    __syncthreads();   // A
    {
        const float4* s1 = reinterpret_cast<const float4*>(pw1 + 2 * kH * kD);
        const float4* s2 = reinterpret_cast<const float4*>(go_w2);
        #pragma unroll
        for (int k = 0; k < 4; ++k) { ra[k] = s1[k * 256 + tid]; rb[k] = s2[k * 256 + tid]; }
        quad_transpose16(qb, l, xq, 0, L, lg);
        quad_transpose16(qb, l, xq, 1, L, lg);
        softmax32(lg, gi);
        #pragma unroll
        for (int k = 0; k < 4; ++k) d4[1024 + k * 256 + tid] = rb[k];
    }
    __syncthreads();   // B
    #pragma unroll
    for (int k = 0; k < 4; ++k) d4[k * 256 + tid] = ra[k];
    __syncthreads();   // C: pass-2 slabs ready

    // ---- pass 2 (g_out) ----
    {
        const float4 B0 = *reinterpret_cast<const float4*>(gob2 + 4 * l);
        const float4 B1 = *reinterpret_cast<const float4*>(gob2 + 16 + 4 * l);
        mlp_pass(hq, w1q, w2q, pb1[256 + lane], pb1[320 + lane], L);
        add_b2_slice(L, B0, B1);
    }
    __syncthreads();   // slabs dead -> scratch
    quad_transpose16(qb, l, xq, 0, L, lg);
    quad_transpose16(qb, l, xq, 1, L, lg);

    // g_out softmax fused with gumbel argmax (y never materialized)
    float m3 = lg[0];
    #pragma unroll
    for (int s = 1; s < kS; ++s) m3 = fmaxf(m3, lg[s]);
    float e3[kS];
    #pragma unroll
    for (int s = 0; s < kS; ++s) e3[s] = expf(lg[s] - m3);
    const float Z3 = tree_sum32(e3);
    const float qs = tree_sum32(q);   // == sum(q), computed like the reference

    float uv[kS];
    {
        const float4* u4 = reinterpret_cast<const float4*>(u + (size_t)b * kS);
        #pragma unroll
        for (int i = 0; i < 8; ++i) {
            float4 t = u4[i];
            uv[4 * i + 0] = t.x; uv[4 * i + 1] = t.y;
            uv[4 * i + 2] = t.z; uv[4 * i + 3] = t.w;
        }
    }

    float best = -__builtin_inff();
    int bi = 0;
    {
        #pragma clang fp contract(off)   // match np's per-op rounding here
        #pragma unroll
        for (int s = 0; s < kS; ++s) {
            const float gos = e3[s] / Z3;
            const float t1 = gi[s] * (qs - q[s]);
            const float t2 = gos * q[s];
            const float qn = q[s] + (t1 + t2);
            const float gn = -logf(-logf(uv[s] + 1e-20f) + 1e-20f);
            const float v  = logf(qn + 1e-12f) + gn;
            if (v > best) { best = v; bi = s; }   // strict >: first-index ties, like np.argmax
        }
    }

    // out[b,:] = table[bi,:]
    const float4* trow = reinterpret_cast<const float4*>(table + (size_t)bi * kS);
    float4* orow = reinterpret_cast<float4*>(out + (size_t)b * kD);
    #pragma unroll
    for (int i = 0; i < 8; ++i) orow[i] = trow[i];
}

extern "C" void kernel_launch(void* const* d_in, const int* in_sizes, int n_in,
                              void* d_out, int out_size, void* d_ws, size_t ws_size,
                              hipStream_t stream)
{
    const float* h      = (const float*)d_in[0];
    const float* u      = (const float*)d_in[1];
    const float* q_w1   = (const float*)d_in[2];
    const float* q_b1   = (const float*)d_in[3];
    const float* q_w2   = (const float*)d_in[4];
    const float* q_b2   = (const float*)d_in[5];
    const float* gi_w1  = (const float*)d_in[6];
    const float* gi_b1  = (const float*)d_in[7];
    const float* gi_w2  = (const float*)d_in[8];
    const float* gi_b2  = (const float*)d_in[9];
    const float* go_w1  = (const float*)d_in[10];
    const float* go_b1  = (const float*)d_in[11];
    const float* go_w2  = (const float*)d_in[12];
    const float* go_b2  = (const float*)d_in[13];
    const float* dec_w1 = (const float*)d_in[14];
    const float* dec_b1 = (const float*)d_in[15];
    const float* dec_w2 = (const float*)d_in[16];
    const float* dec_b2 = (const float*)d_in[17];

    float* pw1   = (float*)d_ws;                       // 49152 B
    float* pb1   = (float*)((char*)d_ws + 49152);      //  1536 B
    float* table = (float*)((char*)d_ws + 50688);      //  4096 B
    float* out   = (float*)d_out;

    prep_kernel<<<1, 1024, 0, stream>>>(q_w1, q_b1, gi_w1, gi_b1, go_w1, go_b1,
                                        dec_w1, dec_b1, dec_w2, dec_b2,
                                        pw1, pb1, table);
    main_kernel<<<kB / 256, 256, 0, stream>>>(h, u, q_b2, gi_b2, go_b2,
                                              q_w2, gi_w2, go_w2,
                                              pw1, pb1, table, out);
}